// Round 1
// 617.116 us; speedup vs baseline: 1.1436x; 1.1436x over previous
//
#include <hip/hip_runtime.h>

// CrossScaleAttention on MI355X — round 6.
// R5 post-mortem: all pipes idle (Mfma 9.9%, VALU 6.4%, HBM 3.8%, occ 24.6%)
// -> latency-serialization: 27 V loads/wave/iter consumed immediately with no
// reg headroom (170-reg cap), Ks re-stage exposed between barriers, 2 full
// barrier drains/iter, Z write stream thrashing per-XCD L2 (evicting V).
// R6: (1) Ks double-buffered + async global_load_lds staging issued at loop
// top (zero VGPR, latency hidden under score+P), (2) Pl double-buffered ->
// ONE barrier per iter (48->24), (3) V register-prefetch: ks0/ks1 groups at
// loop top, ks2 reloaded under ks1 MFMAs, (4) __launch_bounds__(256,2) for
// ~256-reg budget (ILP over TLP; avg occupancy was ~8 waves/CU anyway),
// (5) non-temporal Z stores so V stays L2-resident.
//
// Workspace (101,246,976 B; known-good >= 105.6 MB):
//   xf16 : [4][98][98][32] fp16 match_input, zero halo        2,458,624
//   rkl  : [4][50][50][32] fp16 ref, zero halo                  640,000
//   ef32 : [4][50][50][64] f32 embed_w, zero halo             2,560,000
//   vtp  : [4][576][2304] bf16 V^T (n=tap*64+c, l=ly*48+lx)  10,616,832
//   invn : [4][2304] f32 10/max(norm,1e-4)                       36,864
//   Z    : [nb][9216][576] f32                            nb*21,233,664
// Fallback (ws < 101.2 MB): per-sample loop (37.5 MB).

typedef unsigned short u16;
typedef __attribute__((ext_vector_type(8))) short short8;      // 8 bf16
typedef __attribute__((ext_vector_type(8))) _Float16 half8;    // 8 fp16
typedef __attribute__((ext_vector_type(4))) float f32x4;

__device__ __forceinline__ u16 f2bf(float f) {
    unsigned u = __float_as_uint(f);
    unsigned r = (u + 0x7FFFu + ((u >> 16) & 1u)) >> 16;   // RNE
    return (u16)r;
}
__device__ __forceinline__ float bf2f(u16 h) {
    return __uint_as_float(((unsigned)h) << 16);
}
__device__ __forceinline__ u16 f2h(float f) {
    _Float16 h = (_Float16)f;           // v_cvt_f16_f32 (RNE)
    u16 u; __builtin_memcpy(&u, &h, 2); return u;
}
__device__ __forceinline__ float h2f(u16 u) {
    _Float16 h; __builtin_memcpy(&h, &u, 2); return (float)h;
}

// ---------------------------------------------------------------- zero fill
__global__ void kzero(float4* p, long n) {
    long i = (long)blockIdx.x * blockDim.x + threadIdx.x;
    long st = (long)gridDim.x * blockDim.x;
    float4 z; z.x = 0.f; z.y = 0.f; z.z = 0.f; z.w = 0.f;
    for (; i < n; i += st) p[i] = z;
}

// ------------------------------------------------- match_input -> xf16
__global__ void kmatch(const float* __restrict__ input, const float* __restrict__ w1,
                       const float* __restrict__ b1, const float* __restrict__ a1,
                       u16* __restrict__ xf16) {
    __shared__ float xl[64 * 96];
    __shared__ float wl[32 * 65];
    int b = blockIdx.x / 96, y = blockIdx.x % 96;
    int tid = threadIdx.x;
    for (int i = tid; i < 64 * 96; i += 256) {
        int ci = i / 96, xx = i % 96;
        xl[i] = input[(((b * 64 + ci) * 96) + y) * 96 + xx];
    }
    for (int i = tid; i < 2048; i += 256) wl[(i >> 6) * 65 + (i & 63)] = w1[i];
    __syncthreads();
    float aa = a1[0];
    for (int o = tid; o < 96 * 32; o += 256) {
        int xx = o >> 5, c = o & 31;
        float acc = b1[c];
        #pragma unroll
        for (int ci = 0; ci < 64; ci++) acc = fmaf(xl[ci * 96 + xx], wl[c * 65 + ci], acc);
        float v = acc >= 0.f ? acc : aa * acc;
        xf16[((b * 98 + y + 1) * 98 + (xx + 1)) * 32 + c] = f2h(v);
    }
}

// --------------------- small -> ef32 (embed, f32) + rkl fp16 (ref)
__global__ void ksmall(const float* __restrict__ small, const float* __restrict__ wasm,
                       const float* __restrict__ basm, const float* __restrict__ aasm,
                       const float* __restrict__ wm2, const float* __restrict__ bm2,
                       const float* __restrict__ am2,
                       float* __restrict__ ef32, u16* __restrict__ rkl) {
    __shared__ float sl[64 * 48];
    __shared__ float wa[64 * 65];
    __shared__ float wm[32 * 65];
    int b = blockIdx.x / 48, y = blockIdx.x % 48;
    int tid = threadIdx.x;
    for (int i = tid; i < 64 * 48; i += 256) {
        int ci = i / 48, xx = i % 48;
        sl[i] = small[(((b * 64 + ci) * 48) + y) * 48 + xx];
    }
    for (int i = tid; i < 4096; i += 256) wa[(i >> 6) * 65 + (i & 63)] = wasm[i];
    for (int i = tid; i < 2048; i += 256) wm[(i >> 6) * 65 + (i & 63)] = wm2[i];
    __syncthreads();
    float ae = aasm[0], ar = am2[0];
    for (int o = tid; o < 48 * 64; o += 256) {            // embed_w
        int xx = o >> 6, c = o & 63;
        float acc = basm[c];
        #pragma unroll
        for (int ci = 0; ci < 64; ci++) acc = fmaf(sl[ci * 48 + xx], wa[c * 65 + ci], acc);
        float v = acc >= 0.f ? acc : ae * acc;
        ef32[((b * 50 + y + 1) * 50 + (xx + 1)) * 64 + c] = v;
    }
    for (int o = tid; o < 48 * 32; o += 256) {            // ref -> rkl fp16
        int xx = o >> 5, c = o & 31;
        float acc = bm2[c];
        #pragma unroll
        for (int ci = 0; ci < 64; ci++) acc = fmaf(sl[ci * 48 + xx], wm[c * 65 + ci], acc);
        float v = acc >= 0.f ? acc : ar * acc;
        rkl[((b * 50 + y + 1) * 50 + (xx + 1)) * 32 + c] = f2h(v);
    }
}

// ------------------------------------------------------------ invnorm per key
__global__ void kinvnorm(const u16* __restrict__ rkl, float* __restrict__ invn) {
    int idx = blockIdx.x * 256 + threadIdx.x;   // 9216 exact
    int b = idx / 2304, l = idx % 2304;
    int ly = l / 48, lx = l % 48;
    float s = 0.f;
    for (int ty = 0; ty < 3; ty++)
        for (int tx = 0; tx < 3; tx++) {
            int base = ((b * 50 + ly + ty) * 50 + (lx + tx)) * 32;
            #pragma unroll
            for (int c = 0; c < 32; c++) {
                float v = h2f(rkl[base + c]);
                s = fmaf(v, v, s);
            }
        }
    invn[idx] = 10.f / fmaxf(sqrtf(s), 1e-4f);   // SCALE folded in
}

// ------------------------------------------------------------- pack V^T bf16
// grid = 4*576: one block per (b, n). Coalesced writes, div-free inner loop.
__global__ void kvtp(const float* __restrict__ ef32, u16* __restrict__ vtp) {
    int bi = blockIdx.x;
    int b = bi / 576, n = bi % 576;
    int t = n >> 6, c = n & 63;
    int ty = t / 3, tx = t % 3;
    const float* eb = ef32 + (size_t)b * 50 * 50 * 64 + c;
    u16* vo = vtp + (size_t)(b * 576 + n) * 2304;
    for (int l = threadIdx.x; l < 2304; l += 256) {
        int ly = l / 48, lx = l - ly * 48;
        vo[l] = f2bf(eb[((ly + ty) * 50 + (lx + tx)) * 64]);
    }
}

// ---------------------------------------------- async Ks staging (12800 B)
// Linear copy rb-row-block -> LDS: per-lane global src, wave-uniform LDS base.
__device__ __forceinline__ void stage_ks(const u16* __restrict__ src, u16* dst, int tid) {
    int wb = tid & ~63;   // wave-uniform
    #pragma unroll
    for (int k = 0; k < 3; ++k)
        __builtin_amdgcn_global_load_lds(
            (const __attribute__((address_space(1))) void*)(src + (size_t)(tid + k * 256) * 8),
            (__attribute__((address_space(3))) void*)(dst + (size_t)(wb + k * 256) * 8),
            16, 0, 0);
    if (tid < 32)   // tail: 800*16B total, lanes 0..31 of wave 0
        __builtin_amdgcn_global_load_lds(
            (const __attribute__((address_space(1))) void*)(src + (size_t)(tid + 768) * 8),
            (__attribute__((address_space(3))) void*)(dst + (size_t)768 * 8),
            16, 0, 0);
}

// ------------------------------------------------------------- fused score+PV
// grid = nb*288; block = 256 (4 waves: mh=w&1 -> M-tile, nh=w>>1 -> key half).
// BM=32 queries, BN=96 keys/iter, 24 iters. Q frags in registers.
// Ks double-buffered, DMA-staged at loop top. Pl double-buffered -> ONE
// barrier/iter. V prefetched into regs (ks0/ks1 at top, ks2 under ks1 MFMAs).
// Z stored non-temporally (keep V resident in per-XCD L2).
__launch_bounds__(256, 2)
__global__ void kfused2(const u16* __restrict__ xf16, const u16* __restrict__ rkl,
                        const u16* __restrict__ vtp, const float* __restrict__ invn,
                        float* __restrict__ Z, int b0, int nb) {
    __shared__ u16 Ks[2][6400];     // 25600 B: dbuf, 4 halo rows x [50 px][32 c] fp16
    __shared__ u16 Pl[2][6 * 512];  // 12288 B: dbuf, [(mt*3+kb)*512 + m*32 + kc^8*quad]
    __shared__ float llds[2][32];   //   256 B  -> 38144 B total

    int tid = threadIdx.x;
    int w = tid >> 6, lane = tid & 63, l15 = lane & 15, quad = lane >> 4;
    int mh = w & 1, nh = w >> 1;
    int bi = blockIdx.x, brel, t;
    if (nb == 4) { brel = bi & 3; t = bi >> 2; }   // bi%8 fixes XCD: 1 batch per XCD
    else         { brel = 0; t = bi; }
    int b = b0 + brel;
    int px0 = (t % 6) * 16, pyb = (t / 6) * 2;

    const u16* xb = xf16 + (size_t)b * 98 * 98 * 32;
    const u16* rb = rkl + (size_t)b * 50 * 50 * 32;
    const float* invb = invn + b * 2304;
    const u16* vw = vtp + (size_t)b * 576 * 2304 + (size_t)(w * 144 + l15) * 2304 + quad * 8;

    // Q fragments in registers, loaded once (contiguous 1024 B per frag/wave)
    half8 qf[3][3];
    #pragma unroll
    for (int ty = 0; ty < 3; ++ty)
        #pragma unroll
        for (int tx = 0; tx < 3; ++tx)
            qf[ty][tx] = *(const half8*)(xb + (((pyb + mh + ty) * 98) + (px0 + l15 + tx)) * 32 + quad * 8);

    stage_ks(rb, Ks[0], tid);       // async; drained by the prologue barrier

    f32x4 acc[18];
    #pragma unroll
    for (int i = 0; i < 18; i++) acc[i] = (f32x4)0.f;
    float lacc[4] = {0.f, 0.f, 0.f, 0.f};

    __syncthreads();

    short8 v0[9], v1[9];

    for (int it = 0; it < 24; ++it) {
        int ly0 = it * 2;
        int cur = it & 1;

        // ---- async-issue phase: next Ks (DMA) + this iter's V (regs).
        // All latency hides under score + P; the single barrier drains vmcnt.
        if (it < 23) stage_ks(rb + (ly0 + 2) * 1600, Ks[cur ^ 1], tid);

        const u16* vit = vw + it * 96;
        #pragma unroll
        for (int nt = 0; nt < 9; ++nt) v0[nt] = *(const short8*)(vit + (size_t)nt * 36864);        // ks=0
        #pragma unroll
        for (int nt = 0; nt < 9; ++nt) v1[nt] = *(const short8*)(vit + (size_t)nt * 36864 + 32);   // ks=1

        float invs[3];
        #pragma unroll
        for (int lxo = 0; lxo < 3; ++lxo)
            invs[lxo] = invb[(ly0 + nh) * 48 + lxo * 16 + l15];

        // ---- score: S[16 px of py row pyb+mh, 48 keys of row ly0+nh], fp16
        f32x4 sf[3];
        #pragma unroll
        for (int i = 0; i < 3; i++) sf[i] = (f32x4)0.f;
        const u16* Kc = Ks[cur];
        #pragma unroll
        for (int ty = 0; ty < 3; ++ty)
            #pragma unroll
            for (int tx = 0; tx < 3; ++tx) {
                half8 a = qf[ty][tx];
                #pragma unroll
                for (int lxo = 0; lxo < 3; ++lxo) {
                    half8 bb = *(const half8*)&Kc[(nh + ty) * 1600 + (lxo * 16 + l15 + tx) * 32 + quad * 8];
                    sf[lxo] = __builtin_amdgcn_mfma_f32_16x16x32_f16(a, bb, sf[lxo], 0, 0, 0);
                }
            }

        // ---- p = exp(s*invs) -> Pl[cur] (swizzled); accumulate l
        u16* Pc = Pl[cur];
        #pragma unroll
        for (int lxo = 0; lxo < 3; ++lxo) {
            int k = nh * 48 + lxo * 16 + l15;
            int kb = k >> 5;
            int kc = (k & 31) ^ (quad << 3);   // XOR swizzle by quad
            #pragma unroll
            for (int r = 0; r < 4; ++r) {
                float p = __expf(sf[lxo][r] * invs[lxo]);
                u16 h = f2bf(p);
                Pc[(mh * 3 + kb) * 512 + (quad * 4 + r) * 32 + kc] = h;
                lacc[r] += bf2f(h);   // l exactly as the PV MFMA sees P
            }
        }

        __syncthreads();   // Pl[cur] visible; Ks[cur^1] + v0/v1 landed (vmcnt drain)

        // ---- PV: O[32, this wave's 144 cols] += P[32,96] @ V[96,144], bf16
        const u16* Pr = Pl[cur];
        short8 pa[2];
        // ks = 0 (v0)
        #pragma unroll
        for (int mt = 0; mt < 2; ++mt)
            pa[mt] = *(const short8*)&Pr[(mt * 3 + 0) * 512 + l15 * 32 + ((quad ^ (l15 >> 2)) & 3) * 8];
        #pragma unroll
        for (int nt = 0; nt < 9; ++nt) {
            acc[nt]     = __builtin_amdgcn_mfma_f32_16x16x32_bf16(pa[0], v0[nt], acc[nt], 0, 0, 0);
            acc[9 + nt] = __builtin_amdgcn_mfma_f32_16x16x32_bf16(pa[1], v0[nt], acc[9 + nt], 0, 0, 0);
        }
        // reload v0 <- ks=2 under ks=1 MFMAs
        #pragma unroll
        for (int nt = 0; nt < 9; ++nt)
            v0[nt] = *(const short8*)(vit + (size_t)nt * 36864 + 64);
        // ks = 1 (v1)
        #pragma unroll
        for (int mt = 0; mt < 2; ++mt)
            pa[mt] = *(const short8*)&Pr[(mt * 3 + 1) * 512 + l15 * 32 + ((quad ^ (l15 >> 2)) & 3) * 8];
        #pragma unroll
        for (int nt = 0; nt < 9; ++nt) {
            acc[nt]     = __builtin_amdgcn_mfma_f32_16x16x32_bf16(pa[0], v1[nt], acc[nt], 0, 0, 0);
            acc[9 + nt] = __builtin_amdgcn_mfma_f32_16x16x32_bf16(pa[1], v1[nt], acc[9 + nt], 0, 0, 0);
        }
        // ks = 2 (v0 reloaded)
        #pragma unroll
        for (int mt = 0; mt < 2; ++mt)
            pa[mt] = *(const short8*)&Pr[(mt * 3 + 2) * 512 + l15 * 32 + ((quad ^ (l15 >> 2)) & 3) * 8];
        #pragma unroll
        for (int nt = 0; nt < 9; ++nt) {
            acc[nt]     = __builtin_amdgcn_mfma_f32_16x16x32_bf16(pa[0], v0[nt], acc[nt], 0, 0, 0);
            acc[9 + nt] = __builtin_amdgcn_mfma_f32_16x16x32_bf16(pa[1], v0[nt], acc[9 + nt], 0, 0, 0);
        }
    }

    // ---- epilogue: reduce l over l15, merge nh halves, Z = O/(6l)
    #pragma unroll
    for (int r = 0; r < 4; ++r) {
        float v = lacc[r];
        v += __shfl_xor(v, 1);
        v += __shfl_xor(v, 2);
        v += __shfl_xor(v, 4);
        v += __shfl_xor(v, 8);
        lacc[r] = v;
    }
    if (l15 == 0) {
        #pragma unroll
        for (int r = 0; r < 4; ++r)
            llds[nh][mh * 16 + quad * 4 + r] = lacc[r];
    }
    __syncthreads();
    float rli[2][4];
    #pragma unroll
    for (int mt = 0; mt < 2; ++mt)
        #pragma unroll
        for (int r = 0; r < 4; ++r) {
            int m = mt * 16 + quad * 4 + r;
            rli[mt][r] = 1.0f / ((llds[0][m] + llds[1][m]) * 6.0f);
        }

    float* Zb = Z + (size_t)brel * 9216 * 576;
    #pragma unroll
    for (int mt = 0; mt < 2; ++mt) {
        #pragma unroll
        for (int r = 0; r < 4; ++r) {
            int q = (pyb + mt) * 96 + px0 + quad * 4 + r;
            float rl = rli[mt][r];
            float* zr = Zb + (size_t)q * 576 + w * 144;
            #pragma unroll
            for (int nt = 0; nt < 9; ++nt)
                __builtin_nontemporal_store(acc[mt * 9 + nt][r] * rl, zr + nt * 16 + l15);
        }
    }
}

// ------------------------------------------------------------- gather (Z -> out)
__global__ void kgather(const float* __restrict__ Z, float* __restrict__ out, int b0) {
    __shared__ float zb[2 * 9 * 580];   // 41760 B
    int bi = blockIdx.x;                // nb*96*12
    int brel = bi / (96 * 12);
    int rem = bi % (96 * 12);
    int b = b0 + brel;
    int q = rem / 12, xt = rem % 12;
    int ox0 = xt * 16, p0 = ox0 >> 1;
    const float* Zb = Z + (size_t)brel * 9216 * 576;
    int tid = threadIdx.x;
    for (int id = tid; id < 2592; id += 256) {
        int pi = id / 1296, r2 = id % 1296;
        int pxi = r2 / 144, n4 = r2 % 144;
        int py = q + pi; if (py > 95) py = 95;
        int px = p0 + pxi; if (px > 95) px = 95;
        *(float4*)&zb[(pi * 9 + pxi) * 580 + n4 * 4] =
            *(const float4*)&Zb[(size_t)(py * 96 + px) * 576 + n4 * 4];
    }
    __syncthreads();
    int xi = tid & 15, cq = tid >> 4;
    int ox = ox0 + xi;
    bool oxv = ox <= 190;
    int ntx, txl[2], pxl[2];
    if (xi & 1) { ntx = 2; txl[0] = 0; pxl[0] = (xi + 1) >> 1; txl[1] = 2; pxl[1] = (xi - 1) >> 1; }
    else        { ntx = 1; txl[0] = 1; pxl[0] = xi >> 1; txl[1] = 1; pxl[1] = xi >> 1; }
    int oy0 = 2 * q;
    #pragma unroll
    for (int ck = 0; ck < 4; ++ck) {
        int c = cq + ck * 16;
        float v0 = 0.f, v1 = 0.f;
        for (int j = 0; j < ntx; ++j) {
            int tx = txl[j], pxi = pxl[j];
            v0 += zb[(0 * 9 + pxi) * 580 + (3 + tx) * 64 + c];
            v1 += zb[(1 * 9 + pxi) * 580 + (0 + tx) * 64 + c];
            v1 += zb[(0 * 9 + pxi) * 580 + (6 + tx) * 64 + c];
        }
        if (oxv) {
            float* o = out + (((size_t)(b * 64 + c) * 191 + oy0) * 191 + ox);
            *o = v0;
            if (q < 95) *(o + 191) = v1;
        }
    }
}

// --------------------------------------------------------------------- host
extern "C" void kernel_launch(void* const* d_in, const int* in_sizes, int n_in,
                              void* d_out, int out_size, void* d_ws, size_t ws_size,
                              hipStream_t stream) {
    const float* input = (const float*)d_in[0];
    const float* small = (const float*)d_in[1];
    const float* w1 = (const float*)d_in[2];
    const float* b1 = (const float*)d_in[3];
    const float* a1 = (const float*)d_in[4];
    const float* w2 = (const float*)d_in[5];
    const float* b2 = (const float*)d_in[6];
    const float* a2 = (const float*)d_in[7];
    const float* wa = (const float*)d_in[8];
    const float* ba = (const float*)d_in[9];
    const float* aa = (const float*)d_in[10];

    char* ws = (char*)d_ws;
    u16* xf16 = (u16*)(ws + 0);             //  2,458,624
    u16* rkl = (u16*)(ws + 2458624);        //    640,000
    float* ef = (float*)(ws + 3098624);     //  2,560,000
    u16* vtp = (u16*)(ws + 5658624);        // 10,616,832
    float* invn = (float*)(ws + 16275456);  //     36,864
    const size_t PREP = 16312320;
    float* Zbuf = (float*)(ws + PREP);      // nb*21,233,664
    float* out = (float*)d_out;

    int nb = (ws_size >= (size_t)101246976) ? 4 : 1;

    kzero<<<1024, 256, 0, stream>>>((float4*)ws, 5658624 / 16);   // halo'd arrays
    kmatch<<<384, 256, 0, stream>>>(input, w1, b1, a1, xf16);
    ksmall<<<192, 256, 0, stream>>>(small, wa, ba, aa, w2, b2, a2, ef, rkl);
    kinvnorm<<<36, 256, 0, stream>>>(rkl, invn);
    kvtp<<<2304, 256, 0, stream>>>(ef, vtp);

    for (int b0 = 0; b0 < 4; b0 += nb) {
        kfused2<<<nb * 288, 256, 0, stream>>>(xf16, rkl, vtp, invn, Zbuf, b0, nb);
        kgather<<<nb * 1152, 256, 0, stream>>>(Zbuf, out, b0);
    }
}